// Round 5
// baseline (345.759 us; speedup 1.0000x reference)
//
#include <hip/hip_runtime.h>

#define D_FEAT 64

// ---------- int2 linked-list (src packed with next) ----------

// Per edge: push e onto dst's list; record = (src, next) in ONE 8B slot so
// the chase later touches a single random line per edge instead of two.
__global__ void __launch_bounds__(256) gcn_build_ll2(
        const int* __restrict__ src, const int* __restrict__ dst,
        int* __restrict__ head, int2* __restrict__ rec, int nedge) {
    int e = blockIdx.x * blockDim.x + threadIdx.x;
    if (e >= nedge) return;
    int d = dst[e];
    int old = atomicExch(&head[d], e);
    rec[e] = make_int2(src[e], old);
}

// One 64-lane wave per 8 nodes: 8 independent chain chases interleaved for
// MLP. lane = feature index. Chain state is wave-uniform -> branches are
// uniform (s_cbranch), no divergence cost.
__global__ void __launch_bounds__(256) gcn_aggregate_ll2(
        const float* __restrict__ feat, const int* __restrict__ head,
        const int2* __restrict__ rec, float* __restrict__ out, int nnode) {
    int w = blockIdx.x * (blockDim.x >> 6) + (threadIdx.x >> 6);
    int lane = threadIdx.x & 63;
    int n0 = w * 8;
    if (n0 >= nnode) return;

    int e[8];
    float s[8];
    int c[8];
#pragma unroll
    for (int k = 0; k < 8; ++k) {
        e[k] = (n0 + k < nnode) ? head[n0 + k] : -1;
        s[k] = 0.f;
        c[k] = 0;
    }

    int all;
    do {
#pragma unroll
        for (int k = 0; k < 8; ++k) {
            if (e[k] != -1) {
                int2 r = rec[e[k]];                       // one random 8B line
                s[k] += feat[(long)r.x * D_FEAT + lane];  // 256B row gather
                e[k] = r.y;
                c[k]++;
            }
        }
        all = e[0];
#pragma unroll
        for (int k = 1; k < 8; ++k) all &= e[k];
    } while (all != -1);

#pragma unroll
    for (int k = 0; k < 8; ++k) {
        if (n0 + k < nnode) {
            long o = (long)(n0 + k) * D_FEAT + lane;
            out[o] = s[k] / (float)c[k] + feat[o];
        }
    }
}

// ---------- fallback tier 2: round-4 split linked-list ----------

__global__ void __launch_bounds__(256) gcn_build_ll(
        const int* __restrict__ src, const int* __restrict__ dst,
        int* __restrict__ head, int* __restrict__ next, int nedge) {
    int e = blockIdx.x * blockDim.x + threadIdx.x;
    if (e >= nedge) return;
    int d = dst[e];
    int old = atomicExch(&head[d], e);
    next[e] = old;
}

__global__ void __launch_bounds__(256) gcn_aggregate_ll(
        const float* __restrict__ feat, const int* __restrict__ head,
        const int* __restrict__ next, const int* __restrict__ src,
        float* __restrict__ out, int nnode) {
    int w = blockIdx.x * (blockDim.x >> 6) + (threadIdx.x >> 6);
    int lane = threadIdx.x & 63;
    int n0 = w * 4;
    if (n0 >= nnode) return;
    int e0 = head[n0];
    int e1 = (n0 + 1 < nnode) ? head[n0 + 1] : -1;
    int e2 = (n0 + 2 < nnode) ? head[n0 + 2] : -1;
    int e3 = (n0 + 3 < nnode) ? head[n0 + 3] : -1;
    float s0 = 0.f, s1 = 0.f, s2 = 0.f, s3 = 0.f;
    int c0 = 0, c1 = 0, c2 = 0, c3 = 0;
    while ((e0 & e1 & e2 & e3) != -1) {
        if (e0 != -1) { int sx = src[e0]; int nx = next[e0]; s0 += feat[(long)sx * D_FEAT + lane]; e0 = nx; c0++; }
        if (e1 != -1) { int sx = src[e1]; int nx = next[e1]; s1 += feat[(long)sx * D_FEAT + lane]; e1 = nx; c1++; }
        if (e2 != -1) { int sx = src[e2]; int nx = next[e2]; s2 += feat[(long)sx * D_FEAT + lane]; e2 = nx; c2++; }
        if (e3 != -1) { int sx = src[e3]; int nx = next[e3]; s3 += feat[(long)sx * D_FEAT + lane]; e3 = nx; c3++; }
    }
    long o0 = (long)n0 * D_FEAT + lane;
    out[o0] = s0 / (float)c0 + feat[o0];
    if (n0 + 1 < nnode) { long o = o0 + D_FEAT;     out[o] = s1 / (float)c1 + feat[o]; }
    if (n0 + 2 < nnode) { long o = o0 + 2 * D_FEAT; out[o] = s2 / (float)c2 + feat[o]; }
    if (n0 + 3 < nnode) { long o = o0 + 3 * D_FEAT; out[o] = s3 / (float)c3 + feat[o]; }
}

// ---------- fallback tier 3: direct atomic scatter ----------

__global__ void __launch_bounds__(256) gcn_scatter(
        const float* __restrict__ feat, const int* __restrict__ src,
        const int* __restrict__ dst, float* __restrict__ agg,
        float* __restrict__ deg, int nedge) {
    long t = (long)blockIdx.x * blockDim.x + threadIdx.x;
    int e = (int)(t >> 4);
    int l = (int)(t & 15);
    if (e >= nedge) return;
    int s = src[e];
    int d = dst[e];
    const float4 v = reinterpret_cast<const float4*>(feat + (long)s * D_FEAT)[l];
    float* a = agg + (long)d * D_FEAT + l * 4;
    atomicAdd(a + 0, v.x);
    atomicAdd(a + 1, v.y);
    atomicAdd(a + 2, v.z);
    atomicAdd(a + 3, v.w);
    if (l == 0) atomicAdd(&deg[d], 1.0f);
}

__global__ void __launch_bounds__(256) gcn_finalize(
        const float* __restrict__ in_feat, const float* __restrict__ deg,
        float* __restrict__ out, int nvec) {
    int i = blockIdx.x * blockDim.x + threadIdx.x;
    if (i >= nvec) return;
    int node = i >> 4;
    float dv = deg[node];
    float4 a = reinterpret_cast<float4*>(out)[i];
    float4 f = reinterpret_cast<const float4*>(in_feat)[i];
    float4 r;
    r.x = a.x / dv + f.x;
    r.y = a.y / dv + f.y;
    r.z = a.z / dv + f.z;
    r.w = a.w / dv + f.w;
    reinterpret_cast<float4*>(out)[i] = r;
}

extern "C" void kernel_launch(void* const* d_in, const int* in_sizes, int n_in,
                              void* d_out, int out_size, void* d_ws, size_t ws_size,
                              hipStream_t stream) {
    const float* in_feat = (const float*)d_in[0];
    const int* src       = (const int*)d_in[1];
    const int* dst       = (const int*)d_in[2];
    float* out = (float*)d_out;

    int N     = in_sizes[0] / D_FEAT;
    int nedge = in_sizes[1];
    int block = 256;
    int egrid = (nedge + block - 1) / block;

    size_t need2 = (size_t)nedge * sizeof(int2) + (size_t)N * sizeof(int);
    size_t need1 = ((size_t)N + (size_t)nedge) * sizeof(int);

    if (ws_size >= need2) {
        // tier 1: packed int2 records
        int2* rec = (int2*)d_ws;
        int* head = (int*)(rec + nedge);
        hipMemsetAsync(head, 0xFF, (size_t)N * sizeof(int), stream);  // -1
        gcn_build_ll2<<<egrid, block, 0, stream>>>(src, dst, head, rec, nedge);
        int nodes_per_block = (block / 64) * 8;  // 32
        int agrid = (N + nodes_per_block - 1) / nodes_per_block;
        gcn_aggregate_ll2<<<agrid, block, 0, stream>>>(in_feat, head, rec, out, N);
    } else if (ws_size >= need1) {
        // tier 2: split head/next linked list
        int* head = (int*)d_ws;
        int* next = head + N;
        hipMemsetAsync(head, 0xFF, (size_t)N * sizeof(int), stream);
        gcn_build_ll<<<egrid, block, 0, stream>>>(src, dst, head, next, nedge);
        int nodes_per_block = (block / 64) * 4;  // 16
        int agrid = (N + nodes_per_block - 1) / nodes_per_block;
        gcn_aggregate_ll<<<agrid, block, 0, stream>>>(in_feat, head, next, src, out, N);
    } else {
        // tier 3: direct atomic path
        float* deg = (float*)d_ws;
        hipMemsetAsync(d_out, 0, (size_t)out_size * sizeof(float), stream);
        hipMemsetAsync(deg, 0, (size_t)N * sizeof(float), stream);
        long total_threads = (long)nedge * 16;
        int grid = (int)((total_threads + block - 1) / block);
        gcn_scatter<<<grid, block, 0, stream>>>(in_feat, src, dst, out, deg, nedge);
        int nvec = N * D_FEAT / 4;
        gcn_finalize<<<(nvec + 255) / 256, 256, 0, stream>>>(in_feat, deg, out, nvec);
    }
}

// Round 7
// 323.964 us; speedup vs baseline: 1.0673x; 1.0673x over previous
//
#include <hip/hip_runtime.h>

#define D_FEAT 64
#define NGRP 8

// ---------- tier 1: XCD-group-privatized linked lists ----------

// group = blockIdx & 7 aligns (heuristically) with XCD round-robin dispatch,
// so atomicExch on head[g*N + d] stays in that XCD's L2 — no cross-XCD line
// ping-pong. rec[e] = (src, next) packed, coalesced write.
__global__ void __launch_bounds__(256) gcn_build_g(
        const int* __restrict__ src, const int* __restrict__ dst,
        int* __restrict__ head, int2* __restrict__ rec,
        int nedge, int nnode) {
    int e = blockIdx.x * blockDim.x + threadIdx.x;
    if (e >= nedge) return;
    int g = blockIdx.x & (NGRP - 1);
    int old = atomicExch(&head[(long)g * nnode + dst[e]], e);
    rec[e] = make_int2(src[e], old);
}

// One wave per node (grid-stride); 8 short chains (one per group) interleaved
// into a single accumulator. Serial dependent-load depth = max chain len (~5)
// instead of full degree (~23). lane = feature index.
__global__ void __launch_bounds__(256) gcn_aggregate_g(
        const float* __restrict__ feat, const int* __restrict__ head,
        const int2* __restrict__ rec, float* __restrict__ out, int nnode) {
    int lane = threadIdx.x & 63;
    int wpg = (gridDim.x * blockDim.x) >> 6;  // waves in grid
    int w0 = blockIdx.x * (blockDim.x >> 6) + (threadIdx.x >> 6);

    for (int node = w0; node < nnode; node += wpg) {
        int e[NGRP];
#pragma unroll
        for (int g = 0; g < NGRP; ++g) e[g] = head[(long)g * nnode + node];

        float s = 0.f;
        int c = 0;
        int all;
        do {
#pragma unroll
            for (int g = 0; g < NGRP; ++g) {
                if (e[g] != -1) {                         // wave-uniform branch
                    int2 r = rec[e[g]];                   // one random 8B line
                    s += feat[(long)r.x * D_FEAT + lane]; // 256B row gather
                    e[g] = r.y;
                    c++;
                }
            }
            all = e[0];
#pragma unroll
            for (int g = 1; g < NGRP; ++g) all &= e[g];
        } while (all != -1);

        long o = (long)node * D_FEAT + lane;
        out[o] = s / (float)c + feat[o];
    }
}

// ---------- tier 2: single linked list (round-5 validated path) ----------

__global__ void __launch_bounds__(256) gcn_build_ll2(
        const int* __restrict__ src, const int* __restrict__ dst,
        int* __restrict__ head, int2* __restrict__ rec, int nedge) {
    int e = blockIdx.x * blockDim.x + threadIdx.x;
    if (e >= nedge) return;
    int d = dst[e];
    int old = atomicExch(&head[d], e);
    rec[e] = make_int2(src[e], old);
}

__global__ void __launch_bounds__(256) gcn_aggregate_ll2(
        const float* __restrict__ feat, const int* __restrict__ head,
        const int2* __restrict__ rec, float* __restrict__ out, int nnode) {
    int w = blockIdx.x * (blockDim.x >> 6) + (threadIdx.x >> 6);
    int lane = threadIdx.x & 63;
    int n0 = w * 4;
    if (n0 >= nnode) return;
    int e[4]; float s[4]; int c[4];
#pragma unroll
    for (int k = 0; k < 4; ++k) {
        e[k] = (n0 + k < nnode) ? head[n0 + k] : -1;
        s[k] = 0.f; c[k] = 0;
    }
    int all;
    do {
#pragma unroll
        for (int k = 0; k < 4; ++k) {
            if (e[k] != -1) {
                int2 r = rec[e[k]];
                s[k] += feat[(long)r.x * D_FEAT + lane];
                e[k] = r.y; c[k]++;
            }
        }
        all = e[0] & e[1] & e[2] & e[3];
    } while (all != -1);
#pragma unroll
    for (int k = 0; k < 4; ++k) {
        if (n0 + k < nnode) {
            long o = (long)(n0 + k) * D_FEAT + lane;
            out[o] = s[k] / (float)c[k] + feat[o];
        }
    }
}

// ---------- tier 3: direct atomic scatter ----------

__global__ void __launch_bounds__(256) gcn_scatter(
        const float* __restrict__ feat, const int* __restrict__ src,
        const int* __restrict__ dst, float* __restrict__ agg,
        float* __restrict__ deg, int nedge) {
    long t = (long)blockIdx.x * blockDim.x + threadIdx.x;
    int e = (int)(t >> 4);
    int l = (int)(t & 15);
    if (e >= nedge) return;
    int s = src[e];
    int d = dst[e];
    const float4 v = reinterpret_cast<const float4*>(feat + (long)s * D_FEAT)[l];
    float* a = agg + (long)d * D_FEAT + l * 4;
    atomicAdd(a + 0, v.x);
    atomicAdd(a + 1, v.y);
    atomicAdd(a + 2, v.z);
    atomicAdd(a + 3, v.w);
    if (l == 0) atomicAdd(&deg[d], 1.0f);
}

__global__ void __launch_bounds__(256) gcn_finalize(
        const float* __restrict__ in_feat, const float* __restrict__ deg,
        float* __restrict__ out, int nvec) {
    int i = blockIdx.x * blockDim.x + threadIdx.x;
    if (i >= nvec) return;
    int node = i >> 4;
    float dv = deg[node];
    float4 a = reinterpret_cast<float4*>(out)[i];
    float4 f = reinterpret_cast<const float4*>(in_feat)[i];
    float4 r;
    r.x = a.x / dv + f.x;
    r.y = a.y / dv + f.y;
    r.z = a.z / dv + f.z;
    r.w = a.w / dv + f.w;
    reinterpret_cast<float4*>(out)[i] = r;
}

extern "C" void kernel_launch(void* const* d_in, const int* in_sizes, int n_in,
                              void* d_out, int out_size, void* d_ws, size_t ws_size,
                              hipStream_t stream) {
    const float* in_feat = (const float*)d_in[0];
    const int* src       = (const int*)d_in[1];
    const int* dst       = (const int*)d_in[2];
    float* out = (float*)d_out;

    int N     = in_sizes[0] / D_FEAT;
    int nedge = in_sizes[1];
    int block = 256;
    int egrid = (nedge + block - 1) / block;

    size_t needg = (size_t)nedge * sizeof(int2) + (size_t)NGRP * N * sizeof(int);
    size_t need2 = (size_t)nedge * sizeof(int2) + (size_t)N * sizeof(int);

    if (ws_size >= needg) {
        // tier 1: 8 group-private lists
        int2* rec = (int2*)d_ws;
        int* head = (int*)(rec + nedge);
        hipMemsetAsync(head, 0xFF, (size_t)NGRP * N * sizeof(int), stream); // -1
        gcn_build_g<<<egrid, block, 0, stream>>>(src, dst, head, rec, nedge, N);
        // one wave per node, grid capped at 2048 blocks (8192 waves)
        int nodes_per_block = block / 64;  // 4
        int agrid = (N + nodes_per_block - 1) / nodes_per_block;
        if (agrid > 2048) agrid = 2048;
        gcn_aggregate_g<<<agrid, block, 0, stream>>>(in_feat, head, rec, out, N);
    } else if (ws_size >= need2) {
        // tier 2: single list
        int2* rec = (int2*)d_ws;
        int* head = (int*)(rec + nedge);
        hipMemsetAsync(head, 0xFF, (size_t)N * sizeof(int), stream);
        gcn_build_ll2<<<egrid, block, 0, stream>>>(src, dst, head, rec, nedge);
        int nodes_per_block = (block / 64) * 4;  // 16
        int agrid = (N + nodes_per_block - 1) / nodes_per_block;
        gcn_aggregate_ll2<<<agrid, block, 0, stream>>>(in_feat, head, rec, out, N);
    } else {
        // tier 3: direct atomic path
        float* deg = (float*)d_ws;
        hipMemsetAsync(d_out, 0, (size_t)out_size * sizeof(float), stream);
        hipMemsetAsync(deg, 0, (size_t)N * sizeof(float), stream);
        long total_threads = (long)nedge * 16;
        int grid = (int)((total_threads + block - 1) / block);
        gcn_scatter<<<grid, block, 0, stream>>>(in_feat, src, dst, out, deg, nedge);
        int nvec = N * D_FEAT / 4;
        gcn_finalize<<<(nvec + 255) / 256, 256, 0, stream>>>(in_feat, deg, out, nvec);
    }
}